// Round 5
// baseline (452.842 us; speedup 1.0000x reference)
//
#include <hip/hip_runtime.h>
#include <cmath>

// ---------------------------------------------------------------------------
// WireframeDetector: NMS -> top-k 300 junctions -> line sampling (bilinear +
// maxpool) -> 3-layer MLP (fp16 MFMA for the two 1024x1024 GEMMs).
// R5: R2's proven GEMM inner loop (BK=32, plain lane-monotonic DMA staging)
//     recombined with R3's XCD tile order (FETCH 182->33 MB). R3 failed on
//     fetch-swizzle (broke DMA coalescing); R4 failed on BK=64 row stride
//     (16-way LDS read conflicts, 15.7M cycles). Single-variable experiment.
// ---------------------------------------------------------------------------

typedef _Float16 f16;
typedef _Float16 f16x2 __attribute__((ext_vector_type(2)));
typedef _Float16 f16x8 __attribute__((ext_vector_type(8)));
typedef float f32x4 __attribute__((ext_vector_type(4)));

#define HWD 128
#define NPIX 16384            // 128*128
#define TOPK_N 300
#define NLINES 20000
#define MTILES 160            // 160 m-tiles of 128 rows = 20480 (20 per XCD)
#define KDIM 1024
#define NDIM 1024
#define MAXCAND 4096

// async global->LDS, 16B per lane; LDS dest = wave-uniform base + lane*16
#define G2L(gp, lp) __builtin_amdgcn_global_load_lds( \
    (const __attribute__((address_space(1))) void*)(gp), \
    (__attribute__((address_space(3))) void*)(lp), 16, 0, 0)

// ---------------------------------------------------------------------------
// Transpose loi_features [C][H][W] fp32 -> loiT [H][W][C] fp16, LDS-tiled.
// Side job: block 0 zeros the NMS candidate counter.
// ---------------------------------------------------------------------------
__global__ __launch_bounds__(256) void transpose_loi_kernel(
    const float* __restrict__ loi, f16* __restrict__ loiT, int* __restrict__ count)
{
    if (blockIdx.x == 0 && threadIdx.x == 0) *count = 0;
    __shared__ f16 t[128 * 130];     // [x][c], +2 pad breaks bank conflicts
    const int y = blockIdx.x;        // 128 blocks
    const int tid = threadIdx.x;
    #pragma unroll 4
    for (int it = 0; it < 64; ++it) {
        int idx = it * 256 + tid;    // c-major, x fast -> coalesced read
        int c = idx >> 7, x = idx & 127;
        t[x * 130 + c] = (f16)loi[c * NPIX + y * HWD + x];
    }
    __syncthreads();
    #pragma unroll
    for (int it = 0; it < 8; ++it) {
        int j = it * 256 + tid;      // 2048 chunks of 8 f16
        int x = j >> 4, cc = (j & 15) * 8;
        f16x8 v;
        #pragma unroll
        for (int u = 0; u < 8; ++u) v[u] = t[x * 130 + cc + u];
        *(f16x8*)(loiT + (y * HWD + x) * HWD + cc) = v;
    }
}

// ---------------------------------------------------------------------------
// Transpose W [K][N] fp32 -> Wt [N][K] fp16, 64x64 LDS tiles.
// One dispatch does both W1 (bid<256) and W2.
// ---------------------------------------------------------------------------
__global__ __launch_bounds__(256) void transpose_w_kernel(
    const float* __restrict__ W1, f16* __restrict__ W1T,
    const float* __restrict__ W2, f16* __restrict__ W2T)
{
    const int bid = blockIdx.x;      // 512
    const float* W = (bid < 256) ? W1 : W2;
    f16* Wt = (bid < 256) ? W1T : W2T;
    const int b = bid & 255;
    __shared__ f16 t[64 * 66];
    const int k0 = (b >> 4) * 64;
    const int n0 = (b & 15) * 64;
    const int tid = threadIdx.x;
    #pragma unroll 4
    for (int it = 0; it < 16; ++it) {
        int i = it * 256 + tid;      // coalesced read over n
        int r = i >> 6, c = i & 63;
        t[c * 66 + r] = (f16)W[(size_t)(k0 + r) * NDIM + n0 + c];
    }
    __syncthreads();
    #pragma unroll
    for (int it = 0; it < 2; ++it) {
        int j = it * 256 + tid;
        int nr = j >> 3, kc = (j & 7) * 8;
        f16x8 v;
        #pragma unroll
        for (int u = 0; u < 8; ++u) v[u] = t[nr * 66 + kc + u];
        *(f16x8*)(Wt + (size_t)(n0 + nr) * KDIM + k0 + kc) = v;
    }
}

// ---------------------------------------------------------------------------
// NMS scan, multi-block: survivors -> global candidate list.
// Key = (val_bits << 32) | (~pixel_idx): desc order == value desc, index asc.
// ---------------------------------------------------------------------------
__global__ __launch_bounds__(256) void nms_kernel(
    const float* __restrict__ jloc, unsigned long long* __restrict__ cand,
    int* __restrict__ count)
{
    const int p = blockIdx.x * 256 + threadIdx.x;   // 64 blocks
    const int y = p >> 7, x = p & 127;
    const float c = jloc[p];
    float m = c;
    for (int dy = -1; dy <= 1; ++dy) {
        int yy = y + dy;
        if (yy < 0 || yy >= HWD) continue;
        for (int dx = -1; dx <= 1; ++dx) {
            int xx = x + dx;
            if (xx < 0 || xx >= HWD) continue;
            m = fmaxf(m, jloc[yy * HWD + xx]);
        }
    }
    if (c == m && c > 0.0f) {
        int pos = atomicAdd(count, 1);
        if (pos < MAXCAND) {
            unsigned int ub = __float_as_uint(c);
            cand[pos] = ((unsigned long long)ub << 32) |
                        (unsigned long long)(0xFFFFFFFFu - (unsigned int)p);
        }
    }
}

// ---------------------------------------------------------------------------
// Rank-select top-300: rank = #{keys strictly greater}. Keys unique (idx
// embedded) so ranks are exact; order-independent => deterministic.
// ---------------------------------------------------------------------------
__global__ __launch_bounds__(256) void rank_junc_kernel(
    const unsigned long long* __restrict__ cand, const int* __restrict__ count,
    const float* __restrict__ joff, float* __restrict__ juncs /* [300][2] */)
{
    const int t = blockIdx.x * 256 + threadIdx.x;   // 16 blocks = 4096 threads
    const int n = min(*count, MAXCAND);
    if (t >= n) return;
    const unsigned long long key = cand[t];
    int rank = 0;
    for (int j = 0; j < n; ++j)
        rank += (cand[j] > key) ? 1 : 0;
    if (rank < TOPK_N) {
        unsigned int p = 0xFFFFFFFFu - (unsigned int)(key & 0xFFFFFFFFull);
        // x = idx%w + (sigmoid(joff0)-0.5) + 0.5 = idx%w + sigmoid(joff0)
        float sx = 1.0f / (1.0f + expf(-joff[p]));
        float sy = 1.0f / (1.0f + expf(-joff[NPIX + p]));
        juncs[2 * rank + 0] = (float)(p & 127) + sx;
        juncs[2 * rank + 1] = (float)(p >> 7) + sy;
    }
}

// ---------------------------------------------------------------------------
// Per-line sampling: 32 pts bilinear over loiT[H][W][C], maxpool groups of 4,
// write fp16 feats row. 4 lines/block; lane owns channels 2*lane, 2*lane+1.
// ---------------------------------------------------------------------------
__global__ __launch_bounds__(256) void sample_kernel(
    const f16* __restrict__ loiT, const float* __restrict__ juncs,
    const int* __restrict__ edge_idx, f16* __restrict__ feats)
{
    const int l = blockIdx.x * 4 + (threadIdx.x >> 6);
    const int lane = threadIdx.x & 63;
    const int e0 = edge_idx[2 * l], e1 = edge_idx[2 * l + 1];
    const float ux = juncs[2 * e0], uy = juncs[2 * e0 + 1];
    const float vx = juncs[2 * e1], vy = juncs[2 * e1 + 1];
    const int c2 = lane * 2;

    f16x8 o0, o1;
    #pragma unroll
    for (int p = 0; p < 8; ++p) {
        float m0 = -INFINITY, m1 = -INFINITY;
        #pragma unroll
        for (int jj = 0; jj < 4; ++jj) {
            const int j = p * 4 + jj;
            const float t = (float)j * (1.0f / 31.0f);
            const float px = ux * t + vx * (1.0f - t) - 0.5f;
            const float py = uy * t + vy * (1.0f - t) - 0.5f;
            float fx0 = fminf(fmaxf(floorf(px), 0.0f), 127.0f);
            float fy0 = fminf(fmaxf(floorf(py), 0.0f), 127.0f);
            float fx1 = fminf(fx0 + 1.0f, 127.0f);
            float fy1 = fminf(fy0 + 1.0f, 127.0f);
            int ix0 = (int)fx0, iy0 = (int)fy0, ix1 = (int)fx1, iy1 = (int)fy1;
            float w00 = (fy1 - py) * (fx1 - px);
            float w10 = (py - fy0) * (fx1 - px);
            float w01 = (fy1 - py) * (px - fx0);
            float w11 = (py - fy0) * (px - fx0);
            f16x2 v00 = *(const f16x2*)(loiT + (iy0 * HWD + ix0) * HWD + c2);
            f16x2 v10 = *(const f16x2*)(loiT + (iy1 * HWD + ix0) * HWD + c2);
            f16x2 v01 = *(const f16x2*)(loiT + (iy0 * HWD + ix1) * HWD + c2);
            f16x2 v11 = *(const f16x2*)(loiT + (iy1 * HWD + ix1) * HWD + c2);
            float s0 = (float)v00.x * w00 + (float)v10.x * w10 +
                       (float)v01.x * w01 + (float)v11.x * w11;
            float s1 = (float)v00.y * w00 + (float)v10.y * w10 +
                       (float)v01.y * w01 + (float)v11.y * w11;
            m0 = fmaxf(m0, s0);
            m1 = fmaxf(m1, s1);
        }
        o0[p] = (f16)m0;   // channel c2   -> feats[l, 16*lane + p]
        o1[p] = (f16)m1;   // channel c2+1 -> feats[l, 16*lane + 8 + p]
    }
    f16* dst = feats + (size_t)l * KDIM + lane * 16;
    *(f16x8*)(dst) = o0;
    *(f16x8*)(dst + 8) = o1;
}

// ---------------------------------------------------------------------------
// GEMM: 128x128 tile, BK=32, 256 threads (2x2 waves of 64x64 subtiles),
// plain global_load_lds staging (lane-monotonic, 64B rows — R2's inner loop).
// Tile order: xcd = bid&7, 20 m-tiles/XCD, n-tile inner => A-tile L2 reuse.
// head=0: C = relu(A@Bt^T + bias) stored fp16.
// head=1: v = relu(A@Bt^T + bias); out[m][j] += v . W3  (atomicAdd, + b3 once)
// ---------------------------------------------------------------------------
__global__ __launch_bounds__(256, 2) void gemm_bias_relu_kernel(
    const f16* __restrict__ A, const f16* __restrict__ Bt,
    const float* __restrict__ bias, f16* __restrict__ C,
    const float* __restrict__ W3, const float* __restrict__ b3,
    float* __restrict__ out, int K, int head)
{
    const int tid = threadIdx.x;
    const int wave = tid >> 6, lane = tid & 63;
    const int wm = wave >> 1, wn = wave & 1;
    const int bid = blockIdx.x;               // 1280
    const int xcd = bid & 7;
    const int j = bid >> 3;                   // 0..159
    const int mt = xcd * 20 + (j >> 3);       // 20 m-tiles per XCD
    const int nt = j & 7;
    const int m0 = mt * 128;
    const int n0 = nt * 128;
    const int N = NDIM;

    __shared__ f16 sA[128 * 32];
    __shared__ f16 sB[128 * 32];

    f32x4 acc[4][4];
    #pragma unroll
    for (int mi = 0; mi < 4; ++mi)
        #pragma unroll
        for (int ni = 0; ni < 4; ++ni)
            acc[mi][ni] = (f32x4){0.f, 0.f, 0.f, 0.f};

    // DMA staging: 8 KB per matrix per iter = 8 segs of 1KB (16 rows x 64B).
    // Wave w owns segs {w, w+4} of sA and sB. Lane i: row seg*16 + (i>>2),
    // 16B chunk i&3 -> monotonic per-lane addresses (DMA-coalescing-safe).
    const int rs0 = wave * 16 + (lane >> 2);
    const int rs1 = rs0 + 64;
    const int kc = (lane & 3) * 8;
    const f16* gA0 = A + (size_t)(m0 + rs0) * K + kc;
    const f16* gA1 = A + (size_t)(m0 + rs1) * K + kc;
    const f16* gB0 = Bt + (size_t)(n0 + rs0) * K + kc;
    const f16* gB1 = Bt + (size_t)(n0 + rs1) * K + kc;
    f16* lA0 = sA + wave * 512;               // + lane*16B implicit
    f16* lA1 = sA + (wave + 4) * 512;
    f16* lB0 = sB + wave * 512;
    f16* lB1 = sB + (wave + 4) * 512;

    const int col16 = lane & 15;
    const int kq = (lane >> 4) * 8;

    for (int k0 = 0; k0 < K; k0 += 32) {
        __syncthreads();                      // prev iter's LDS reads complete
        G2L(gA0 + k0, lA0);
        G2L(gA1 + k0, lA1);
        G2L(gB0 + k0, lB0);
        G2L(gB1 + k0, lB1);
        __builtin_amdgcn_s_waitcnt(0x0f70);   // vmcnt(0): own DMA done
        __syncthreads();                      // all waves' DMA done

        f16x8 af[4], bf[4];
        #pragma unroll
        for (int i = 0; i < 4; ++i) {
            af[i] = *(const f16x8*)(sA + (wm * 64 + i * 16 + col16) * 32 + kq);
            bf[i] = *(const f16x8*)(sB + (wn * 64 + i * 16 + col16) * 32 + kq);
        }
        #pragma unroll
        for (int mi = 0; mi < 4; ++mi)
            #pragma unroll
            for (int ni = 0; ni < 4; ++ni)
                acc[mi][ni] = __builtin_amdgcn_mfma_f32_16x16x32_f16(
                    af[mi], bf[ni], acc[mi][ni], 0, 0, 0);
    }

    const int quad = lane >> 4;
    if (!head) {
        #pragma unroll
        for (int ni = 0; ni < 4; ++ni) {
            const int n = n0 + wn * 64 + ni * 16 + col16;
            const float b = bias[n];
            #pragma unroll
            for (int mi = 0; mi < 4; ++mi) {
                #pragma unroll
                for (int r = 0; r < 4; ++r) {
                    const int m = m0 + wm * 64 + mi * 16 + quad * 4 + r;
                    float v = fmaxf(acc[mi][ni][r] + b, 0.f);
                    C[(size_t)m * N + n] = (f16)v;
                }
            }
        }
    } else {
        float bb[4], w3c[4][3];
        #pragma unroll
        for (int ni = 0; ni < 4; ++ni) {
            const int n = n0 + wn * 64 + ni * 16 + col16;
            bb[ni] = bias[n];
            #pragma unroll
            for (int jj = 0; jj < 3; ++jj) w3c[ni][jj] = W3[n * 3 + jj];
        }
        const bool addb3 = (nt == 0 && wn == 0);
        #pragma unroll
        for (int mi = 0; mi < 4; ++mi) {
            #pragma unroll
            for (int r = 0; r < 4; ++r) {
                float s0 = 0.f, s1 = 0.f, s2 = 0.f;
                #pragma unroll
                for (int ni = 0; ni < 4; ++ni) {
                    float v = fmaxf(acc[mi][ni][r] + bb[ni], 0.f);
                    s0 += v * w3c[ni][0];
                    s1 += v * w3c[ni][1];
                    s2 += v * w3c[ni][2];
                }
                #pragma unroll
                for (int mask = 1; mask <= 8; mask <<= 1) {
                    s0 += __shfl_xor(s0, mask);
                    s1 += __shfl_xor(s1, mask);
                    s2 += __shfl_xor(s2, mask);
                }
                if (col16 == 0) {
                    const int m = m0 + wm * 64 + mi * 16 + quad * 4 + r;
                    if (m < NLINES) {
                        atomicAdd(&out[m * 3 + 0], s0 + (addb3 ? b3[0] : 0.f));
                        atomicAdd(&out[m * 3 + 1], s1 + (addb3 ? b3[1] : 0.f));
                        atomicAdd(&out[m * 3 + 2], s2 + (addb3 ? b3[2] : 0.f));
                    }
                }
            }
        }
    }
}

// ---------------------------------------------------------------------------
extern "C" void kernel_launch(void* const* d_in, const int* in_sizes, int n_in,
                              void* d_out, int out_size, void* d_ws, size_t ws_size,
                              hipStream_t stream)
{
    const float* jloc = (const float*)d_in[0];
    const float* joff = (const float*)d_in[1];
    const float* loi  = (const float*)d_in[2];
    const int*   eidx = (const int*)d_in[3];
    const float* W1   = (const float*)d_in[4];
    const float* b1   = (const float*)d_in[5];
    const float* W2   = (const float*)d_in[6];
    const float* b2   = (const float*)d_in[7];
    const float* W3   = (const float*)d_in[8];
    const float* b3   = (const float*)d_in[9];
    float* out = (float*)d_out;

    char* ws = (char*)d_ws;
    f16*   loiT  = (f16*)(ws);                            // 4 MB
    f16*   W1T   = (f16*)(ws + ((size_t)4 << 20));        // 2 MB
    f16*   W2T   = (f16*)(ws + ((size_t)6 << 20));        // 2 MB
    float* juncs = (float*)(ws + ((size_t)8 << 20));      // 2.4 KB
    int*   count = (int*)(ws + ((size_t)8 << 20) + 4096);
    unsigned long long* cand =
        (unsigned long long*)(ws + ((size_t)8 << 20) + 8192);  // 32 KB
    f16*   feats = (f16*)(ws + ((size_t)9 << 20));        // 40 MB (MROWS x 1024)
    f16*   h1    = (f16*)(ws + ((size_t)51 << 20));       // 40 MB

    hipMemsetAsync(out, 0, (size_t)out_size * sizeof(float), stream);
    transpose_loi_kernel<<<dim3(HWD), dim3(256), 0, stream>>>(loi, loiT, count);
    transpose_w_kernel<<<dim3(512), dim3(256), 0, stream>>>(W1, W1T, W2, W2T);
    nms_kernel<<<dim3(64), dim3(256), 0, stream>>>(jloc, cand, count);
    rank_junc_kernel<<<dim3(MAXCAND / 256), dim3(256), 0, stream>>>(
        cand, count, joff, juncs);
    sample_kernel<<<dim3(NLINES / 4), dim3(256), 0, stream>>>(loiT, juncs, eidx, feats);
    gemm_bias_relu_kernel<<<dim3(MTILES * 8), dim3(256), 0, stream>>>(
        feats, W1T, b1, h1, nullptr, nullptr, nullptr, KDIM, 0);
    gemm_bias_relu_kernel<<<dim3(MTILES * 8), dim3(256), 0, stream>>>(
        h1, W2T, b2, nullptr, W3, b3, out, KDIM, 1);
}

// Round 6
// 409.895 us; speedup vs baseline: 1.1048x; 1.1048x over previous
//
#include <hip/hip_runtime.h>
#include <cmath>

// ---------------------------------------------------------------------------
// WireframeDetector: NMS -> top-k 300 junctions -> line sampling (bilinear +
// maxpool) -> 3-layer MLP (fp16 MFMA for the two 1024x1024 GEMMs).
// R6: revert XCD tile order (R5 proved it hot-spots L2: FETCH 33MB but
//     hbm 3000->446 GB/s, dur 2x). Natural 2D grid + BN=256 tile to halve
//     A-traffic the non-hot-spotting way. Fused preproc dispatch.
// ---------------------------------------------------------------------------

typedef _Float16 f16;
typedef _Float16 f16x2 __attribute__((ext_vector_type(2)));
typedef _Float16 f16x8 __attribute__((ext_vector_type(8)));
typedef float f32x4 __attribute__((ext_vector_type(4)));

#define HWD 128
#define NPIX 16384            // 128*128
#define TOPK_N 300
#define NLINES 20000
#define MPAD 20096            // 157 * 128
#define KDIM 1024
#define NDIM 1024
#define MAXCAND 4096

// async global->LDS, 16B per lane; LDS dest = wave-uniform base + lane*16
#define G2L(gp, lp) __builtin_amdgcn_global_load_lds( \
    (const __attribute__((address_space(1))) void*)(gp), \
    (__attribute__((address_space(3))) void*)(lp), 16, 0, 0)

// ---------------------------------------------------------------------------
// Fused preprocessing, one dispatch of 704 blocks:
//   blocks 0..127   : transpose loi [C][H][W] fp32 -> loiT [H][W][C] fp16
//   blocks 128..639 : transpose W1/W2 [K][N] fp32 -> [N][K] fp16
//   blocks 640..703 : 3x3 NMS on jloc, survivors -> cand list (count pre-zeroed)
// All three read only inputs; no inter-range dependencies.
// ---------------------------------------------------------------------------
__global__ __launch_bounds__(256) void preproc_kernel(
    const float* __restrict__ loi, f16* __restrict__ loiT,
    const float* __restrict__ W1, f16* __restrict__ W1T,
    const float* __restrict__ W2, f16* __restrict__ W2T,
    const float* __restrict__ jloc, unsigned long long* __restrict__ cand,
    int* __restrict__ count)
{
    const int bid = blockIdx.x;
    const int tid = threadIdx.x;
    if (bid < 128) {
        __shared__ f16 t[128 * 130];     // [x][c], +2 pad kills bank conflicts
        const int y = bid;
        #pragma unroll 4
        for (int it = 0; it < 64; ++it) {
            int idx = it * 256 + tid;    // c-major, x fast -> coalesced read
            int c = idx >> 7, x = idx & 127;
            t[x * 130 + c] = (f16)loi[c * NPIX + y * HWD + x];
        }
        __syncthreads();
        #pragma unroll
        for (int it = 0; it < 8; ++it) {
            int j = it * 256 + tid;      // 2048 chunks of 8 f16
            int x = j >> 4, cc = (j & 15) * 8;
            f16x8 v;
            #pragma unroll
            for (int u = 0; u < 8; ++u) v[u] = t[x * 130 + cc + u];
            *(f16x8*)(loiT + (y * HWD + x) * HWD + cc) = v;
        }
    } else if (bid < 640) {
        const int b = bid - 128;         // 0..511
        const float* W = (b < 256) ? W1 : W2;
        f16* Wt = (b < 256) ? W1T : W2T;
        const int bb = b & 255;
        __shared__ f16 t[64 * 66];
        const int k0 = (bb >> 4) * 64;
        const int n0 = (bb & 15) * 64;
        #pragma unroll 4
        for (int it = 0; it < 16; ++it) {
            int i = it * 256 + tid;      // coalesced read over n
            int r = i >> 6, c = i & 63;
            t[c * 66 + r] = (f16)W[(size_t)(k0 + r) * NDIM + n0 + c];
        }
        __syncthreads();
        #pragma unroll
        for (int it = 0; it < 2; ++it) {
            int j = it * 256 + tid;
            int nr = j >> 3, kc = (j & 7) * 8;
            f16x8 v;
            #pragma unroll
            for (int u = 0; u < 8; ++u) v[u] = t[nr * 66 + kc + u];
            *(f16x8*)(Wt + (size_t)(n0 + nr) * KDIM + k0 + kc) = v;
        }
    } else {
        const int p = (bid - 640) * 256 + tid;   // 64 blocks x 256 = 16384
        const int y = p >> 7, x = p & 127;
        const float c = jloc[p];
        float m = c;
        for (int dy = -1; dy <= 1; ++dy) {
            int yy = y + dy;
            if (yy < 0 || yy >= HWD) continue;
            for (int dx = -1; dx <= 1; ++dx) {
                int xx = x + dx;
                if (xx < 0 || xx >= HWD) continue;
                m = fmaxf(m, jloc[yy * HWD + xx]);
            }
        }
        if (c == m && c > 0.0f) {
            int pos = atomicAdd(count, 1);
            if (pos < MAXCAND) {
                unsigned int ub = __float_as_uint(c);
                cand[pos] = ((unsigned long long)ub << 32) |
                            (unsigned long long)(0xFFFFFFFFu - (unsigned int)p);
            }
        }
    }
}

// ---------------------------------------------------------------------------
// Rank-select top-300: rank = #{keys strictly greater}. Keys unique (idx
// embedded) so ranks are exact; order-independent => deterministic. Matches
// jax.lax.top_k order (value desc, index asc on value ties).
// ---------------------------------------------------------------------------
__global__ __launch_bounds__(256) void rank_junc_kernel(
    const unsigned long long* __restrict__ cand, const int* __restrict__ count,
    const float* __restrict__ joff, float* __restrict__ juncs /* [300][2] */)
{
    const int t = blockIdx.x * 256 + threadIdx.x;   // 16 blocks = 4096 threads
    const int n = min(*count, MAXCAND);
    if (t >= n) return;
    const unsigned long long key = cand[t];
    int rank = 0;
    for (int j = 0; j < n; ++j)
        rank += (cand[j] > key) ? 1 : 0;
    if (rank < TOPK_N) {
        unsigned int p = 0xFFFFFFFFu - (unsigned int)(key & 0xFFFFFFFFull);
        // x = idx%w + (sigmoid(joff0)-0.5) + 0.5 = idx%w + sigmoid(joff0)
        float sx = 1.0f / (1.0f + expf(-joff[p]));
        float sy = 1.0f / (1.0f + expf(-joff[NPIX + p]));
        juncs[2 * rank + 0] = (float)(p & 127) + sx;
        juncs[2 * rank + 1] = (float)(p >> 7) + sy;
    }
}

// ---------------------------------------------------------------------------
// Per-line sampling: 32 pts bilinear over loiT[H][W][C], maxpool groups of 4,
// write fp16 feats row. 4 lines/block; lane owns channels 2*lane, 2*lane+1.
// ---------------------------------------------------------------------------
__global__ __launch_bounds__(256) void sample_kernel(
    const f16* __restrict__ loiT, const float* __restrict__ juncs,
    const int* __restrict__ edge_idx, f16* __restrict__ feats)
{
    const int l = blockIdx.x * 4 + (threadIdx.x >> 6);
    const int lane = threadIdx.x & 63;
    const int e0 = edge_idx[2 * l], e1 = edge_idx[2 * l + 1];
    const float ux = juncs[2 * e0], uy = juncs[2 * e0 + 1];
    const float vx = juncs[2 * e1], vy = juncs[2 * e1 + 1];
    const int c2 = lane * 2;

    f16x8 o0, o1;
    #pragma unroll
    for (int p = 0; p < 8; ++p) {
        float m0 = -INFINITY, m1 = -INFINITY;
        #pragma unroll
        for (int jj = 0; jj < 4; ++jj) {
            const int j = p * 4 + jj;
            const float t = (float)j * (1.0f / 31.0f);
            const float px = ux * t + vx * (1.0f - t) - 0.5f;
            const float py = uy * t + vy * (1.0f - t) - 0.5f;
            float fx0 = fminf(fmaxf(floorf(px), 0.0f), 127.0f);
            float fy0 = fminf(fmaxf(floorf(py), 0.0f), 127.0f);
            float fx1 = fminf(fx0 + 1.0f, 127.0f);
            float fy1 = fminf(fy0 + 1.0f, 127.0f);
            int ix0 = (int)fx0, iy0 = (int)fy0, ix1 = (int)fx1, iy1 = (int)fy1;
            float w00 = (fy1 - py) * (fx1 - px);
            float w10 = (py - fy0) * (fx1 - px);
            float w01 = (fy1 - py) * (px - fx0);
            float w11 = (py - fy0) * (px - fx0);
            f16x2 v00 = *(const f16x2*)(loiT + (iy0 * HWD + ix0) * HWD + c2);
            f16x2 v10 = *(const f16x2*)(loiT + (iy1 * HWD + ix0) * HWD + c2);
            f16x2 v01 = *(const f16x2*)(loiT + (iy0 * HWD + ix1) * HWD + c2);
            f16x2 v11 = *(const f16x2*)(loiT + (iy1 * HWD + ix1) * HWD + c2);
            float s0 = (float)v00.x * w00 + (float)v10.x * w10 +
                       (float)v01.x * w01 + (float)v11.x * w11;
            float s1 = (float)v00.y * w00 + (float)v10.y * w10 +
                       (float)v01.y * w01 + (float)v11.y * w11;
            m0 = fmaxf(m0, s0);
            m1 = fmaxf(m1, s1);
        }
        o0[p] = (f16)m0;   // channel c2   -> feats[l, 16*lane + p]
        o1[p] = (f16)m1;   // channel c2+1 -> feats[l, 16*lane + 8 + p]
    }
    f16* dst = feats + (size_t)l * KDIM + lane * 16;
    *(f16x8*)(dst) = o0;
    *(f16x8*)(dst + 8) = o1;
}

// ---------------------------------------------------------------------------
// GEMM: 128x256 tile, BK=32, 256 threads. Wave (wm,wn): rows wm*64..+64,
// cols wn*128..+128; acc[4][8] 16x16 subtiles. Plain lane-monotonic
// global_load_lds staging (R2's proven pattern), natural 2D grid (x=m
// fastest: distinct A-tiles stream in parallel, B L2-resident).
// head=0: C = relu(A@Bt^T + bias) stored fp16.
// head=1: v = relu(A@Bt^T + bias); out[m][j] += v . W3  (atomicAdd, + b3 once)
// ---------------------------------------------------------------------------
__global__ __launch_bounds__(256, 2) void gemm_bias_relu_kernel(
    const f16* __restrict__ A, const f16* __restrict__ Bt,
    const float* __restrict__ bias, f16* __restrict__ C,
    const float* __restrict__ W3, const float* __restrict__ b3,
    float* __restrict__ out, int K, int head)
{
    const int tid = threadIdx.x;
    const int wave = tid >> 6, lane = tid & 63;
    const int wm = wave >> 1, wn = wave & 1;
    const int m0 = blockIdx.x * 128;
    const int n0 = blockIdx.y * 256;
    const int N = NDIM;

    __shared__ f16 sA[128 * 32];      // 8 KB
    __shared__ f16 sB[256 * 32];      // 16 KB

    f32x4 acc[4][8];
    #pragma unroll
    for (int mi = 0; mi < 4; ++mi)
        #pragma unroll
        for (int ni = 0; ni < 8; ++ni)
            acc[mi][ni] = (f32x4){0.f, 0.f, 0.f, 0.f};

    // Staging: 1KB segs (16 rows x 64B). sA = 8 segs, wave owns {w, w+4};
    // sB = 16 segs, wave owns {w, w+4, w+8, w+12}. Lane i: row seg*16+(i>>2),
    // 16B chunk i&3 -> monotonic per-lane addresses (DMA-coalescing-safe).
    const int srow = lane >> 2;
    const int kc = (lane & 3) * 8;
    const f16* gA0 = A + (size_t)(m0 + wave * 16 + srow) * K + kc;
    const f16* gA1 = A + (size_t)(m0 + (wave + 4) * 16 + srow) * K + kc;
    f16* lA0 = sA + wave * 512;       // + lane*16B implicit
    f16* lA1 = sA + (wave + 4) * 512;
    const f16* gB[4];
    f16* lB[4];
    #pragma unroll
    for (int s = 0; s < 4; ++s) {
        const int seg = wave + s * 4;
        gB[s] = Bt + (size_t)(n0 + seg * 16 + srow) * K + kc;
        lB[s] = sB + seg * 512;
    }

    const int col16 = lane & 15;
    const int kq = (lane >> 4) * 8;

    for (int k0 = 0; k0 < K; k0 += 32) {
        __syncthreads();                      // prev iter's LDS reads complete
        G2L(gA0 + k0, lA0);
        G2L(gA1 + k0, lA1);
        #pragma unroll
        for (int s = 0; s < 4; ++s) G2L(gB[s] + k0, lB[s]);
        __builtin_amdgcn_s_waitcnt(0x0f70);   // vmcnt(0): own DMA done
        __syncthreads();                      // all waves' DMA done

        f16x8 af[4], bf[8];
        #pragma unroll
        for (int i = 0; i < 4; ++i)
            af[i] = *(const f16x8*)(sA + (wm * 64 + i * 16 + col16) * 32 + kq);
        #pragma unroll
        for (int i = 0; i < 8; ++i)
            bf[i] = *(const f16x8*)(sB + (wn * 128 + i * 16 + col16) * 32 + kq);
        #pragma unroll
        for (int mi = 0; mi < 4; ++mi)
            #pragma unroll
            for (int ni = 0; ni < 8; ++ni)
                acc[mi][ni] = __builtin_amdgcn_mfma_f32_16x16x32_f16(
                    af[mi], bf[ni], acc[mi][ni], 0, 0, 0);
    }

    const int quad = lane >> 4;
    if (!head) {
        #pragma unroll
        for (int ni = 0; ni < 8; ++ni) {
            const int n = n0 + wn * 128 + ni * 16 + col16;
            const float b = bias[n];
            #pragma unroll
            for (int mi = 0; mi < 4; ++mi) {
                #pragma unroll
                for (int r = 0; r < 4; ++r) {
                    const int m = m0 + wm * 64 + mi * 16 + quad * 4 + r;
                    float v = fmaxf(acc[mi][ni][r] + b, 0.f);
                    C[(size_t)m * N + n] = (f16)v;
                }
            }
        }
    } else {
        float bb[8], w3c[8][3];
        #pragma unroll
        for (int ni = 0; ni < 8; ++ni) {
            const int n = n0 + wn * 128 + ni * 16 + col16;
            bb[ni] = bias[n];
            #pragma unroll
            for (int jj = 0; jj < 3; ++jj) w3c[ni][jj] = W3[n * 3 + jj];
        }
        const bool addb3 = (blockIdx.y == 0 && wn == 0);
        #pragma unroll
        for (int mi = 0; mi < 4; ++mi) {
            #pragma unroll
            for (int r = 0; r < 4; ++r) {
                float s0 = 0.f, s1 = 0.f, s2 = 0.f;
                #pragma unroll
                for (int ni = 0; ni < 8; ++ni) {
                    float v = fmaxf(acc[mi][ni][r] + bb[ni], 0.f);
                    s0 += v * w3c[ni][0];
                    s1 += v * w3c[ni][1];
                    s2 += v * w3c[ni][2];
                }
                #pragma unroll
                for (int mask = 1; mask <= 8; mask <<= 1) {
                    s0 += __shfl_xor(s0, mask);
                    s1 += __shfl_xor(s1, mask);
                    s2 += __shfl_xor(s2, mask);
                }
                if (col16 == 0) {
                    const int m = m0 + wm * 64 + mi * 16 + quad * 4 + r;
                    if (m < NLINES) {
                        atomicAdd(&out[m * 3 + 0], s0 + (addb3 ? b3[0] : 0.f));
                        atomicAdd(&out[m * 3 + 1], s1 + (addb3 ? b3[1] : 0.f));
                        atomicAdd(&out[m * 3 + 2], s2 + (addb3 ? b3[2] : 0.f));
                    }
                }
            }
        }
    }
}

// ---------------------------------------------------------------------------
extern "C" void kernel_launch(void* const* d_in, const int* in_sizes, int n_in,
                              void* d_out, int out_size, void* d_ws, size_t ws_size,
                              hipStream_t stream)
{
    const float* jloc = (const float*)d_in[0];
    const float* joff = (const float*)d_in[1];
    const float* loi  = (const float*)d_in[2];
    const int*   eidx = (const int*)d_in[3];
    const float* W1   = (const float*)d_in[4];
    const float* b1   = (const float*)d_in[5];
    const float* W2   = (const float*)d_in[6];
    const float* b2   = (const float*)d_in[7];
    const float* W3   = (const float*)d_in[8];
    const float* b3   = (const float*)d_in[9];
    float* out = (float*)d_out;

    char* ws = (char*)d_ws;
    f16*   loiT  = (f16*)(ws);                            // 4 MB
    f16*   W1T   = (f16*)(ws + ((size_t)4 << 20));        // 2 MB
    f16*   W2T   = (f16*)(ws + ((size_t)6 << 20));        // 2 MB
    float* juncs = (float*)(ws + ((size_t)8 << 20));      // 2.4 KB
    int*   count = (int*)(ws + ((size_t)8 << 20) + 4096);
    unsigned long long* cand =
        (unsigned long long*)(ws + ((size_t)8 << 20) + 8192);  // 32 KB
    f16*   feats = (f16*)(ws + ((size_t)9 << 20));        // 40 MB (MPAD x 1024)
    f16*   h1    = (f16*)(ws + ((size_t)51 << 20));       // 40 MB

    hipMemsetAsync(out, 0, (size_t)out_size * sizeof(float), stream);
    hipMemsetAsync(count, 0, sizeof(int), stream);
    preproc_kernel<<<dim3(704), dim3(256), 0, stream>>>(
        loi, loiT, W1, W1T, W2, W2T, jloc, cand, count);
    rank_junc_kernel<<<dim3(MAXCAND / 256), dim3(256), 0, stream>>>(
        cand, count, joff, juncs);
    sample_kernel<<<dim3(NLINES / 4), dim3(256), 0, stream>>>(loiT, juncs, eidx, feats);
    gemm_bias_relu_kernel<<<dim3(MPAD / 128, NDIM / 256), dim3(256), 0, stream>>>(
        feats, W1T, b1, h1, nullptr, nullptr, nullptr, KDIM, 0);
    gemm_bias_relu_kernel<<<dim3(MPAD / 128, NDIM / 256), dim3(256), 0, stream>>>(
        h1, W2T, b2, nullptr, W3, b3, out, KDIM, 1);
}

// Round 7
// 357.033 us; speedup vs baseline: 1.2683x; 1.1481x over previous
//
#include <hip/hip_runtime.h>
#include <cmath>

// ---------------------------------------------------------------------------
// WireframeDetector: NMS -> top-k 300 junctions -> line sampling (bilinear +
// maxpool) -> 3-layer MLP (fp16 MFMA for the two 1024x1024 GEMMs).
// R7: GEMM reverted to R2's proven config (128x128, BK=32, natural grid —
//     78 us; BN=256 cost occupancy, XCD order hot-spotted L2). rank_junc
//     fixed: LDS-cached keys (was 107 us of serial global reads on 16 CUs).
// ---------------------------------------------------------------------------

typedef _Float16 f16;
typedef _Float16 f16x2 __attribute__((ext_vector_type(2)));
typedef _Float16 f16x8 __attribute__((ext_vector_type(8)));
typedef float f32x4 __attribute__((ext_vector_type(4)));

#define HWD 128
#define NPIX 16384            // 128*128
#define TOPK_N 300
#define NLINES 20000
#define MPAD 20096            // 157 * 128
#define KDIM 1024
#define NDIM 1024
#define MAXCAND 4096

// async global->LDS, 16B per lane; LDS dest = wave-uniform base + lane*16
#define G2L(gp, lp) __builtin_amdgcn_global_load_lds( \
    (const __attribute__((address_space(1))) void*)(gp), \
    (__attribute__((address_space(3))) void*)(lp), 16, 0, 0)

// ---------------------------------------------------------------------------
// Fused preprocessing, one dispatch of 704 blocks:
//   blocks 0..127   : transpose loi [C][H][W] fp32 -> loiT [H][W][C] fp16
//   blocks 128..639 : transpose W1/W2 [K][N] fp32 -> [N][K] fp16
//   blocks 640..703 : 3x3 NMS on jloc, survivors -> cand list (count pre-zeroed)
// ---------------------------------------------------------------------------
__global__ __launch_bounds__(256) void preproc_kernel(
    const float* __restrict__ loi, f16* __restrict__ loiT,
    const float* __restrict__ W1, f16* __restrict__ W1T,
    const float* __restrict__ W2, f16* __restrict__ W2T,
    const float* __restrict__ jloc, unsigned long long* __restrict__ cand,
    int* __restrict__ count)
{
    const int bid = blockIdx.x;
    const int tid = threadIdx.x;
    if (bid < 128) {
        __shared__ f16 t[128 * 130];     // [x][c], +2 pad kills bank conflicts
        const int y = bid;
        #pragma unroll 4
        for (int it = 0; it < 64; ++it) {
            int idx = it * 256 + tid;    // c-major, x fast -> coalesced read
            int c = idx >> 7, x = idx & 127;
            t[x * 130 + c] = (f16)loi[c * NPIX + y * HWD + x];
        }
        __syncthreads();
        #pragma unroll
        for (int it = 0; it < 8; ++it) {
            int j = it * 256 + tid;      // 2048 chunks of 8 f16
            int x = j >> 4, cc = (j & 15) * 8;
            f16x8 v;
            #pragma unroll
            for (int u = 0; u < 8; ++u) v[u] = t[x * 130 + cc + u];
            *(f16x8*)(loiT + (y * HWD + x) * HWD + cc) = v;
        }
    } else if (bid < 640) {
        const int b = bid - 128;         // 0..511
        const float* W = (b < 256) ? W1 : W2;
        f16* Wt = (b < 256) ? W1T : W2T;
        const int bb = b & 255;
        __shared__ f16 t[64 * 66];
        const int k0 = (bb >> 4) * 64;
        const int n0 = (bb & 15) * 64;
        #pragma unroll 4
        for (int it = 0; it < 16; ++it) {
            int i = it * 256 + tid;      // coalesced read over n
            int r = i >> 6, c = i & 63;
            t[c * 66 + r] = (f16)W[(size_t)(k0 + r) * NDIM + n0 + c];
        }
        __syncthreads();
        #pragma unroll
        for (int it = 0; it < 2; ++it) {
            int j = it * 256 + tid;
            int nr = j >> 3, kc = (j & 7) * 8;
            f16x8 v;
            #pragma unroll
            for (int u = 0; u < 8; ++u) v[u] = t[nr * 66 + kc + u];
            *(f16x8*)(Wt + (size_t)(n0 + nr) * KDIM + k0 + kc) = v;
        }
    } else {
        const int p = (bid - 640) * 256 + tid;   // 64 blocks x 256 = 16384
        const int y = p >> 7, x = p & 127;
        const float c = jloc[p];
        float m = c;
        for (int dy = -1; dy <= 1; ++dy) {
            int yy = y + dy;
            if (yy < 0 || yy >= HWD) continue;
            for (int dx = -1; dx <= 1; ++dx) {
                int xx = x + dx;
                if (xx < 0 || xx >= HWD) continue;
                m = fmaxf(m, jloc[yy * HWD + xx]);
            }
        }
        if (c == m && c > 0.0f) {
            int pos = atomicAdd(count, 1);
            if (pos < MAXCAND) {
                unsigned int ub = __float_as_uint(c);
                cand[pos] = ((unsigned long long)ub << 32) |
                            (unsigned long long)(0xFFFFFFFFu - (unsigned int)p);
            }
        }
    }
}

// ---------------------------------------------------------------------------
// Rank-select top-300, LDS-cached: each block copies the full candidate list
// into LDS, then each thread ranks one key against LDS (was: 1820 serial
// GLOBAL reads per thread on a 16-CU grid = 107 us latency-bound).
// Keys unique => ranks exact; matches jax.lax.top_k order.
// ---------------------------------------------------------------------------
__global__ __launch_bounds__(256) void rank_junc_kernel(
    const unsigned long long* __restrict__ cand, const int* __restrict__ count,
    const float* __restrict__ joff, float* __restrict__ juncs /* [300][2] */)
{
    __shared__ unsigned long long keys[MAXCAND];   // 32 KB
    const int n = min(*count, MAXCAND);
    const int t = blockIdx.x * 256 + threadIdx.x;  // 16 blocks = 4096 threads
    for (int i = threadIdx.x; i < n; i += 256)
        keys[i] = cand[i];
    __syncthreads();
    if (t >= n) return;
    const unsigned long long key = keys[t];
    int rank = 0;
    int j = 0;
    for (; j + 4 <= n; j += 4) {
        rank += (keys[j]     > key);
        rank += (keys[j + 1] > key);
        rank += (keys[j + 2] > key);
        rank += (keys[j + 3] > key);
    }
    for (; j < n; ++j) rank += (keys[j] > key);
    if (rank < TOPK_N) {
        unsigned int p = 0xFFFFFFFFu - (unsigned int)(key & 0xFFFFFFFFull);
        // x = idx%w + (sigmoid(joff0)-0.5) + 0.5 = idx%w + sigmoid(joff0)
        float sx = 1.0f / (1.0f + expf(-joff[p]));
        float sy = 1.0f / (1.0f + expf(-joff[NPIX + p]));
        juncs[2 * rank + 0] = (float)(p & 127) + sx;
        juncs[2 * rank + 1] = (float)(p >> 7) + sy;
    }
}

// ---------------------------------------------------------------------------
// Per-line sampling: 32 pts bilinear over loiT[H][W][C], maxpool groups of 4,
// write fp16 feats row. 4 lines/block; lane owns channels 2*lane, 2*lane+1.
// ---------------------------------------------------------------------------
__global__ __launch_bounds__(256) void sample_kernel(
    const f16* __restrict__ loiT, const float* __restrict__ juncs,
    const int* __restrict__ edge_idx, f16* __restrict__ feats)
{
    const int l = blockIdx.x * 4 + (threadIdx.x >> 6);
    const int lane = threadIdx.x & 63;
    const int e0 = edge_idx[2 * l], e1 = edge_idx[2 * l + 1];
    const float ux = juncs[2 * e0], uy = juncs[2 * e0 + 1];
    const float vx = juncs[2 * e1], vy = juncs[2 * e1 + 1];
    const int c2 = lane * 2;

    f16x8 o0, o1;
    #pragma unroll
    for (int p = 0; p < 8; ++p) {
        float m0 = -INFINITY, m1 = -INFINITY;
        #pragma unroll
        for (int jj = 0; jj < 4; ++jj) {
            const int j = p * 4 + jj;
            const float t = (float)j * (1.0f / 31.0f);
            const float px = ux * t + vx * (1.0f - t) - 0.5f;
            const float py = uy * t + vy * (1.0f - t) - 0.5f;
            float fx0 = fminf(fmaxf(floorf(px), 0.0f), 127.0f);
            float fy0 = fminf(fmaxf(floorf(py), 0.0f), 127.0f);
            float fx1 = fminf(fx0 + 1.0f, 127.0f);
            float fy1 = fminf(fy0 + 1.0f, 127.0f);
            int ix0 = (int)fx0, iy0 = (int)fy0, ix1 = (int)fx1, iy1 = (int)fy1;
            float w00 = (fy1 - py) * (fx1 - px);
            float w10 = (py - fy0) * (fx1 - px);
            float w01 = (fy1 - py) * (px - fx0);
            float w11 = (py - fy0) * (px - fx0);
            f16x2 v00 = *(const f16x2*)(loiT + (iy0 * HWD + ix0) * HWD + c2);
            f16x2 v10 = *(const f16x2*)(loiT + (iy1 * HWD + ix0) * HWD + c2);
            f16x2 v01 = *(const f16x2*)(loiT + (iy0 * HWD + ix1) * HWD + c2);
            f16x2 v11 = *(const f16x2*)(loiT + (iy1 * HWD + ix1) * HWD + c2);
            float s0 = (float)v00.x * w00 + (float)v10.x * w10 +
                       (float)v01.x * w01 + (float)v11.x * w11;
            float s1 = (float)v00.y * w00 + (float)v10.y * w10 +
                       (float)v01.y * w01 + (float)v11.y * w11;
            m0 = fmaxf(m0, s0);
            m1 = fmaxf(m1, s1);
        }
        o0[p] = (f16)m0;   // channel c2   -> feats[l, 16*lane + p]
        o1[p] = (f16)m1;   // channel c2+1 -> feats[l, 16*lane + 8 + p]
    }
    f16* dst = feats + (size_t)l * KDIM + lane * 16;
    *(f16x8*)(dst) = o0;
    *(f16x8*)(dst + 8) = o1;
}

// ---------------------------------------------------------------------------
// GEMM: 128x128 tile, BK=32, 256 threads (2x2 waves of 64x64 subtiles),
// plain lane-monotonic global_load_lds staging, natural 2D grid (R2's
// proven 78us config — latency-bound loop; traffic-saving trades all lost).
// head=0: C = relu(A@Bt^T + bias) stored fp16.
// head=1: v = relu(A@Bt^T + bias); out[m][j] += v . W3  (atomicAdd, + b3 once)
// ---------------------------------------------------------------------------
__global__ __launch_bounds__(256, 2) void gemm_bias_relu_kernel(
    const f16* __restrict__ A, const f16* __restrict__ Bt,
    const float* __restrict__ bias, f16* __restrict__ C,
    const float* __restrict__ W3, const float* __restrict__ b3,
    float* __restrict__ out, int K, int head)
{
    const int tid = threadIdx.x;
    const int wave = tid >> 6, lane = tid & 63;
    const int wm = wave >> 1, wn = wave & 1;
    const int m0 = blockIdx.x * 128;
    const int n0 = blockIdx.y * 128;
    const int N = NDIM;

    __shared__ f16 sA[128 * 32];
    __shared__ f16 sB[128 * 32];

    f32x4 acc[4][4];
    #pragma unroll
    for (int mi = 0; mi < 4; ++mi)
        #pragma unroll
        for (int ni = 0; ni < 4; ++ni)
            acc[mi][ni] = (f32x4){0.f, 0.f, 0.f, 0.f};

    // DMA staging: 8 KB per matrix per iter = 8 segs of 1KB (16 rows x 64B).
    // Wave w owns segs {w, w+4} of sA and sB. Lane i: row seg*16 + (i>>2),
    // 16B chunk i&3 -> monotonic per-lane addresses (DMA-coalescing-safe).
    const int rs0 = wave * 16 + (lane >> 2);
    const int rs1 = rs0 + 64;
    const int kc = (lane & 3) * 8;
    const f16* gA0 = A + (size_t)(m0 + rs0) * K + kc;
    const f16* gA1 = A + (size_t)(m0 + rs1) * K + kc;
    const f16* gB0 = Bt + (size_t)(n0 + rs0) * K + kc;
    const f16* gB1 = Bt + (size_t)(n0 + rs1) * K + kc;
    f16* lA0 = sA + wave * 512;               // + lane*16B implicit
    f16* lA1 = sA + (wave + 4) * 512;
    f16* lB0 = sB + wave * 512;
    f16* lB1 = sB + (wave + 4) * 512;

    const int col16 = lane & 15;
    const int kq = (lane >> 4) * 8;

    for (int k0 = 0; k0 < K; k0 += 32) {
        __syncthreads();                      // prev iter's LDS reads complete
        G2L(gA0 + k0, lA0);
        G2L(gA1 + k0, lA1);
        G2L(gB0 + k0, lB0);
        G2L(gB1 + k0, lB1);
        __builtin_amdgcn_s_waitcnt(0x0f70);   // vmcnt(0): own DMA done
        __syncthreads();                      // all waves' DMA done

        f16x8 af[4], bf[4];
        #pragma unroll
        for (int i = 0; i < 4; ++i) {
            af[i] = *(const f16x8*)(sA + (wm * 64 + i * 16 + col16) * 32 + kq);
            bf[i] = *(const f16x8*)(sB + (wn * 64 + i * 16 + col16) * 32 + kq);
        }
        #pragma unroll
        for (int mi = 0; mi < 4; ++mi)
            #pragma unroll
            for (int ni = 0; ni < 4; ++ni)
                acc[mi][ni] = __builtin_amdgcn_mfma_f32_16x16x32_f16(
                    af[mi], bf[ni], acc[mi][ni], 0, 0, 0);
    }

    const int quad = lane >> 4;
    if (!head) {
        #pragma unroll
        for (int ni = 0; ni < 4; ++ni) {
            const int n = n0 + wn * 64 + ni * 16 + col16;
            const float b = bias[n];
            #pragma unroll
            for (int mi = 0; mi < 4; ++mi) {
                #pragma unroll
                for (int r = 0; r < 4; ++r) {
                    const int m = m0 + wm * 64 + mi * 16 + quad * 4 + r;
                    float v = fmaxf(acc[mi][ni][r] + b, 0.f);
                    C[(size_t)m * N + n] = (f16)v;
                }
            }
        }
    } else {
        float bb[4], w3c[4][3];
        #pragma unroll
        for (int ni = 0; ni < 4; ++ni) {
            const int n = n0 + wn * 64 + ni * 16 + col16;
            bb[ni] = bias[n];
            #pragma unroll
            for (int jj = 0; jj < 3; ++jj) w3c[ni][jj] = W3[n * 3 + jj];
        }
        const bool addb3 = (blockIdx.y == 0 && wn == 0);
        #pragma unroll
        for (int mi = 0; mi < 4; ++mi) {
            #pragma unroll
            for (int r = 0; r < 4; ++r) {
                float s0 = 0.f, s1 = 0.f, s2 = 0.f;
                #pragma unroll
                for (int ni = 0; ni < 4; ++ni) {
                    float v = fmaxf(acc[mi][ni][r] + bb[ni], 0.f);
                    s0 += v * w3c[ni][0];
                    s1 += v * w3c[ni][1];
                    s2 += v * w3c[ni][2];
                }
                #pragma unroll
                for (int mask = 1; mask <= 8; mask <<= 1) {
                    s0 += __shfl_xor(s0, mask);
                    s1 += __shfl_xor(s1, mask);
                    s2 += __shfl_xor(s2, mask);
                }
                if (col16 == 0) {
                    const int m = m0 + wm * 64 + mi * 16 + quad * 4 + r;
                    if (m < NLINES) {
                        atomicAdd(&out[m * 3 + 0], s0 + (addb3 ? b3[0] : 0.f));
                        atomicAdd(&out[m * 3 + 1], s1 + (addb3 ? b3[1] : 0.f));
                        atomicAdd(&out[m * 3 + 2], s2 + (addb3 ? b3[2] : 0.f));
                    }
                }
            }
        }
    }
}

// ---------------------------------------------------------------------------
extern "C" void kernel_launch(void* const* d_in, const int* in_sizes, int n_in,
                              void* d_out, int out_size, void* d_ws, size_t ws_size,
                              hipStream_t stream)
{
    const float* jloc = (const float*)d_in[0];
    const float* joff = (const float*)d_in[1];
    const float* loi  = (const float*)d_in[2];
    const int*   eidx = (const int*)d_in[3];
    const float* W1   = (const float*)d_in[4];
    const float* b1   = (const float*)d_in[5];
    const float* W2   = (const float*)d_in[6];
    const float* b2   = (const float*)d_in[7];
    const float* W3   = (const float*)d_in[8];
    const float* b3   = (const float*)d_in[9];
    float* out = (float*)d_out;

    char* ws = (char*)d_ws;
    f16*   loiT  = (f16*)(ws);                            // 4 MB
    f16*   W1T   = (f16*)(ws + ((size_t)4 << 20));        // 2 MB
    f16*   W2T   = (f16*)(ws + ((size_t)6 << 20));        // 2 MB
    float* juncs = (float*)(ws + ((size_t)8 << 20));      // 2.4 KB
    int*   count = (int*)(ws + ((size_t)8 << 20) + 4096);
    unsigned long long* cand =
        (unsigned long long*)(ws + ((size_t)8 << 20) + 8192);  // 32 KB
    f16*   feats = (f16*)(ws + ((size_t)9 << 20));        // 40 MB (MPAD x 1024)
    f16*   h1    = (f16*)(ws + ((size_t)51 << 20));       // 40 MB

    hipMemsetAsync(out, 0, (size_t)out_size * sizeof(float), stream);
    hipMemsetAsync(count, 0, sizeof(int), stream);
    preproc_kernel<<<dim3(704), dim3(256), 0, stream>>>(
        loi, loiT, W1, W1T, W2, W2T, jloc, cand, count);
    rank_junc_kernel<<<dim3(MAXCAND / 256), dim3(256), 0, stream>>>(
        cand, count, joff, juncs);
    sample_kernel<<<dim3(NLINES / 4), dim3(256), 0, stream>>>(loiT, juncs, eidx, feats);
    gemm_bias_relu_kernel<<<dim3(MPAD / 128, NDIM / 128), dim3(256), 0, stream>>>(
        feats, W1T, b1, h1, nullptr, nullptr, nullptr, KDIM, 0);
    gemm_bias_relu_kernel<<<dim3(MPAD / 128, NDIM / 128), dim3(256), 0, stream>>>(
        h1, W2T, b2, nullptr, W3, b3, out, KDIM, 1);
}

// Round 8
// 346.083 us; speedup vs baseline: 1.3085x; 1.0316x over previous
//
#include <hip/hip_runtime.h>
#include <cmath>

// ---------------------------------------------------------------------------
// WireframeDetector: NMS -> top-k 300 junctions -> line sampling (bilinear +
// maxpool) -> 3-layer MLP (fp16 MFMA for the two 1024x1024 GEMMs).
// R8: GEMM stages TWO BK=32 tiles per round into separate 8KB buffers
//     (64B row stride preserved -> no new bank conflicts, unlike R4's BK=64)
//     => one vmcnt(0)+barrier drain per 32 MFMAs instead of per 16.
// ---------------------------------------------------------------------------

typedef _Float16 f16;
typedef _Float16 f16x2 __attribute__((ext_vector_type(2)));
typedef _Float16 f16x8 __attribute__((ext_vector_type(8)));
typedef float f32x4 __attribute__((ext_vector_type(4)));

#define HWD 128
#define NPIX 16384            // 128*128
#define TOPK_N 300
#define NLINES 20000
#define MPAD 20096            // 157 * 128
#define KDIM 1024
#define NDIM 1024
#define MAXCAND 4096

// async global->LDS, 16B per lane; LDS dest = wave-uniform base + lane*16
#define G2L(gp, lp) __builtin_amdgcn_global_load_lds( \
    (const __attribute__((address_space(1))) void*)(gp), \
    (__attribute__((address_space(3))) void*)(lp), 16, 0, 0)

// ---------------------------------------------------------------------------
// Fused preprocessing, one dispatch of 704 blocks:
//   blocks 0..127   : transpose loi [C][H][W] fp32 -> loiT [H][W][C] fp16
//   blocks 128..639 : transpose W1/W2 [K][N] fp32 -> [N][K] fp16
//   blocks 640..703 : 3x3 NMS on jloc, survivors -> cand list (count pre-zeroed)
// ---------------------------------------------------------------------------
__global__ __launch_bounds__(256) void preproc_kernel(
    const float* __restrict__ loi, f16* __restrict__ loiT,
    const float* __restrict__ W1, f16* __restrict__ W1T,
    const float* __restrict__ W2, f16* __restrict__ W2T,
    const float* __restrict__ jloc, unsigned long long* __restrict__ cand,
    int* __restrict__ count)
{
    const int bid = blockIdx.x;
    const int tid = threadIdx.x;
    if (bid < 128) {
        __shared__ f16 t[128 * 130];     // [x][c], +2 pad kills bank conflicts
        const int y = bid;
        #pragma unroll 4
        for (int it = 0; it < 64; ++it) {
            int idx = it * 256 + tid;    // c-major, x fast -> coalesced read
            int c = idx >> 7, x = idx & 127;
            t[x * 130 + c] = (f16)loi[c * NPIX + y * HWD + x];
        }
        __syncthreads();
        #pragma unroll
        for (int it = 0; it < 8; ++it) {
            int j = it * 256 + tid;      // 2048 chunks of 8 f16
            int x = j >> 4, cc = (j & 15) * 8;
            f16x8 v;
            #pragma unroll
            for (int u = 0; u < 8; ++u) v[u] = t[x * 130 + cc + u];
            *(f16x8*)(loiT + (y * HWD + x) * HWD + cc) = v;
        }
    } else if (bid < 640) {
        const int b = bid - 128;         // 0..511
        const float* W = (b < 256) ? W1 : W2;
        f16* Wt = (b < 256) ? W1T : W2T;
        const int bb = b & 255;
        __shared__ f16 t[64 * 66];
        const int k0 = (bb >> 4) * 64;
        const int n0 = (bb & 15) * 64;
        #pragma unroll 4
        for (int it = 0; it < 16; ++it) {
            int i = it * 256 + tid;      // coalesced read over n
            int r = i >> 6, c = i & 63;
            t[c * 66 + r] = (f16)W[(size_t)(k0 + r) * NDIM + n0 + c];
        }
        __syncthreads();
        #pragma unroll
        for (int it = 0; it < 2; ++it) {
            int j = it * 256 + tid;
            int nr = j >> 3, kc = (j & 7) * 8;
            f16x8 v;
            #pragma unroll
            for (int u = 0; u < 8; ++u) v[u] = t[nr * 66 + kc + u];
            *(f16x8*)(Wt + (size_t)(n0 + nr) * KDIM + k0 + kc) = v;
        }
    } else {
        const int p = (bid - 640) * 256 + tid;   // 64 blocks x 256 = 16384
        const int y = p >> 7, x = p & 127;
        const float c = jloc[p];
        float m = c;
        for (int dy = -1; dy <= 1; ++dy) {
            int yy = y + dy;
            if (yy < 0 || yy >= HWD) continue;
            for (int dx = -1; dx <= 1; ++dx) {
                int xx = x + dx;
                if (xx < 0 || xx >= HWD) continue;
                m = fmaxf(m, jloc[yy * HWD + xx]);
            }
        }
        if (c == m && c > 0.0f) {
            int pos = atomicAdd(count, 1);
            if (pos < MAXCAND) {
                unsigned int ub = __float_as_uint(c);
                cand[pos] = ((unsigned long long)ub << 32) |
                            (unsigned long long)(0xFFFFFFFFu - (unsigned int)p);
            }
        }
    }
}

// ---------------------------------------------------------------------------
// Rank-select top-300, LDS-cached. Keys unique => ranks exact; matches
// jax.lax.top_k order (value desc, index asc).
// ---------------------------------------------------------------------------
__global__ __launch_bounds__(256) void rank_junc_kernel(
    const unsigned long long* __restrict__ cand, const int* __restrict__ count,
    const float* __restrict__ joff, float* __restrict__ juncs /* [300][2] */)
{
    __shared__ unsigned long long keys[MAXCAND];   // 32 KB
    const int n = min(*count, MAXCAND);
    const int t = blockIdx.x * 256 + threadIdx.x;  // 16 blocks = 4096 threads
    for (int i = threadIdx.x; i < n; i += 256)
        keys[i] = cand[i];
    __syncthreads();
    if (t >= n) return;
    const unsigned long long key = keys[t];
    int rank = 0;
    int j = 0;
    for (; j + 4 <= n; j += 4) {
        rank += (keys[j]     > key);
        rank += (keys[j + 1] > key);
        rank += (keys[j + 2] > key);
        rank += (keys[j + 3] > key);
    }
    for (; j < n; ++j) rank += (keys[j] > key);
    if (rank < TOPK_N) {
        unsigned int p = 0xFFFFFFFFu - (unsigned int)(key & 0xFFFFFFFFull);
        // x = idx%w + (sigmoid(joff0)-0.5) + 0.5 = idx%w + sigmoid(joff0)
        float sx = 1.0f / (1.0f + expf(-joff[p]));
        float sy = 1.0f / (1.0f + expf(-joff[NPIX + p]));
        juncs[2 * rank + 0] = (float)(p & 127) + sx;
        juncs[2 * rank + 1] = (float)(p >> 7) + sy;
    }
}

// ---------------------------------------------------------------------------
// Per-line sampling: 32 pts bilinear over loiT[H][W][C], maxpool groups of 4,
// write fp16 feats row. 4 lines/block; lane owns channels 2*lane, 2*lane+1.
// ---------------------------------------------------------------------------
__global__ __launch_bounds__(256) void sample_kernel(
    const f16* __restrict__ loiT, const float* __restrict__ juncs,
    const int* __restrict__ edge_idx, f16* __restrict__ feats)
{
    const int l = blockIdx.x * 4 + (threadIdx.x >> 6);
    const int lane = threadIdx.x & 63;
    const int e0 = edge_idx[2 * l], e1 = edge_idx[2 * l + 1];
    const float ux = juncs[2 * e0], uy = juncs[2 * e0 + 1];
    const float vx = juncs[2 * e1], vy = juncs[2 * e1 + 1];
    const int c2 = lane * 2;

    f16x8 o0, o1;
    #pragma unroll
    for (int p = 0; p < 8; ++p) {
        float m0 = -INFINITY, m1 = -INFINITY;
        #pragma unroll
        for (int jj = 0; jj < 4; ++jj) {
            const int j = p * 4 + jj;
            const float t = (float)j * (1.0f / 31.0f);
            const float px = ux * t + vx * (1.0f - t) - 0.5f;
            const float py = uy * t + vy * (1.0f - t) - 0.5f;
            float fx0 = fminf(fmaxf(floorf(px), 0.0f), 127.0f);
            float fy0 = fminf(fmaxf(floorf(py), 0.0f), 127.0f);
            float fx1 = fminf(fx0 + 1.0f, 127.0f);
            float fy1 = fminf(fy0 + 1.0f, 127.0f);
            int ix0 = (int)fx0, iy0 = (int)fy0, ix1 = (int)fx1, iy1 = (int)fy1;
            float w00 = (fy1 - py) * (fx1 - px);
            float w10 = (py - fy0) * (fx1 - px);
            float w01 = (fy1 - py) * (px - fx0);
            float w11 = (py - fy0) * (px - fx0);
            f16x2 v00 = *(const f16x2*)(loiT + (iy0 * HWD + ix0) * HWD + c2);
            f16x2 v10 = *(const f16x2*)(loiT + (iy1 * HWD + ix0) * HWD + c2);
            f16x2 v01 = *(const f16x2*)(loiT + (iy0 * HWD + ix1) * HWD + c2);
            f16x2 v11 = *(const f16x2*)(loiT + (iy1 * HWD + ix1) * HWD + c2);
            float s0 = (float)v00.x * w00 + (float)v10.x * w10 +
                       (float)v01.x * w01 + (float)v11.x * w11;
            float s1 = (float)v00.y * w00 + (float)v10.y * w10 +
                       (float)v01.y * w01 + (float)v11.y * w11;
            m0 = fmaxf(m0, s0);
            m1 = fmaxf(m1, s1);
        }
        o0[p] = (f16)m0;   // channel c2   -> feats[l, 16*lane + p]
        o1[p] = (f16)m1;   // channel c2+1 -> feats[l, 16*lane + 8 + p]
    }
    f16* dst = feats + (size_t)l * KDIM + lane * 16;
    *(f16x8*)(dst) = o0;
    *(f16x8*)(dst + 8) = o1;
}

// ---------------------------------------------------------------------------
// GEMM: 128x128 tile, 256 threads (2x2 waves of 64x64 subtiles). Per round,
// TWO BK=32 tiles staged into separate 8KB buffers (sA0/sA1/sB0/sB1, 64B row
// stride each -> same bank behavior as the proven BK=32 loop), then one
// vmcnt(0)+barrier drain covers 32 MFMAs. Natural 2D grid.
// head=0: C = relu(A@Bt^T + bias) stored fp16.
// head=1: v = relu(A@Bt^T + bias); out[m][j] += v . W3  (atomicAdd, + b3 once)
// ---------------------------------------------------------------------------
__global__ __launch_bounds__(256, 2) void gemm_bias_relu_kernel(
    const f16* __restrict__ A, const f16* __restrict__ Bt,
    const float* __restrict__ bias, f16* __restrict__ C,
    const float* __restrict__ W3, const float* __restrict__ b3,
    float* __restrict__ out, int K, int head)
{
    const int tid = threadIdx.x;
    const int wave = tid >> 6, lane = tid & 63;
    const int wm = wave >> 1, wn = wave & 1;
    const int m0 = blockIdx.x * 128;
    const int n0 = blockIdx.y * 128;
    const int N = NDIM;

    __shared__ f16 sA0[128 * 32];
    __shared__ f16 sA1[128 * 32];
    __shared__ f16 sB0[128 * 32];
    __shared__ f16 sB1[128 * 32];

    f32x4 acc[4][4];
    #pragma unroll
    for (int mi = 0; mi < 4; ++mi)
        #pragma unroll
        for (int ni = 0; ni < 4; ++ni)
            acc[mi][ni] = (f32x4){0.f, 0.f, 0.f, 0.f};

    // DMA staging (per 8KB buffer): 8 segs of 1KB (16 rows x 64B). Wave w
    // owns segs {w, w+4}. Lane i: row seg*16 + (i>>2), 16B chunk i&3 ->
    // monotonic per-lane addresses (DMA-coalescing-safe).
    const int rs0 = wave * 16 + (lane >> 2);
    const int rs1 = rs0 + 64;
    const int kc = (lane & 3) * 8;
    const f16* gA0 = A + (size_t)(m0 + rs0) * K + kc;
    const f16* gA1 = A + (size_t)(m0 + rs1) * K + kc;
    const f16* gB0 = Bt + (size_t)(n0 + rs0) * K + kc;
    const f16* gB1 = Bt + (size_t)(n0 + rs1) * K + kc;
    const int so0 = wave * 512;               // + lane*16B implicit
    const int so1 = (wave + 4) * 512;

    const int col16 = lane & 15;
    const int kq = (lane >> 4) * 8;

    for (int k0 = 0; k0 < K; k0 += 64) {
        __syncthreads();                      // prev round's LDS reads complete
        G2L(gA0 + k0, sA0 + so0);
        G2L(gA1 + k0, sA0 + so1);
        G2L(gB0 + k0, sB0 + so0);
        G2L(gB1 + k0, sB0 + so1);
        G2L(gA0 + k0 + 32, sA1 + so0);
        G2L(gA1 + k0 + 32, sA1 + so1);
        G2L(gB0 + k0 + 32, sB1 + so0);
        G2L(gB1 + k0 + 32, sB1 + so1);
        __builtin_amdgcn_s_waitcnt(0x0f70);   // vmcnt(0): own DMA done
        __syncthreads();                      // all waves' DMA done

        {
            f16x8 af[4], bf[4];
            #pragma unroll
            for (int i = 0; i < 4; ++i) {
                af[i] = *(const f16x8*)(sA0 + (wm * 64 + i * 16 + col16) * 32 + kq);
                bf[i] = *(const f16x8*)(sB0 + (wn * 64 + i * 16 + col16) * 32 + kq);
            }
            #pragma unroll
            for (int mi = 0; mi < 4; ++mi)
                #pragma unroll
                for (int ni = 0; ni < 4; ++ni)
                    acc[mi][ni] = __builtin_amdgcn_mfma_f32_16x16x32_f16(
                        af[mi], bf[ni], acc[mi][ni], 0, 0, 0);
        }
        {
            f16x8 af[4], bf[4];
            #pragma unroll
            for (int i = 0; i < 4; ++i) {
                af[i] = *(const f16x8*)(sA1 + (wm * 64 + i * 16 + col16) * 32 + kq);
                bf[i] = *(const f16x8*)(sB1 + (wn * 64 + i * 16 + col16) * 32 + kq);
            }
            #pragma unroll
            for (int mi = 0; mi < 4; ++mi)
                #pragma unroll
                for (int ni = 0; ni < 4; ++ni)
                    acc[mi][ni] = __builtin_amdgcn_mfma_f32_16x16x32_f16(
                        af[mi], bf[ni], acc[mi][ni], 0, 0, 0);
        }
    }

    const int quad = lane >> 4;
    if (!head) {
        #pragma unroll
        for (int ni = 0; ni < 4; ++ni) {
            const int n = n0 + wn * 64 + ni * 16 + col16;
            const float b = bias[n];
            #pragma unroll
            for (int mi = 0; mi < 4; ++mi) {
                #pragma unroll
                for (int r = 0; r < 4; ++r) {
                    const int m = m0 + wm * 64 + mi * 16 + quad * 4 + r;
                    float v = fmaxf(acc[mi][ni][r] + b, 0.f);
                    C[(size_t)m * N + n] = (f16)v;
                }
            }
        }
    } else {
        float bb[4], w3c[4][3];
        #pragma unroll
        for (int ni = 0; ni < 4; ++ni) {
            const int n = n0 + wn * 64 + ni * 16 + col16;
            bb[ni] = bias[n];
            #pragma unroll
            for (int jj = 0; jj < 3; ++jj) w3c[ni][jj] = W3[n * 3 + jj];
        }
        const bool addb3 = (blockIdx.y == 0 && wn == 0);
        #pragma unroll
        for (int mi = 0; mi < 4; ++mi) {
            #pragma unroll
            for (int r = 0; r < 4; ++r) {
                float s0 = 0.f, s1 = 0.f, s2 = 0.f;
                #pragma unroll
                for (int ni = 0; ni < 4; ++ni) {
                    float v = fmaxf(acc[mi][ni][r] + bb[ni], 0.f);
                    s0 += v * w3c[ni][0];
                    s1 += v * w3c[ni][1];
                    s2 += v * w3c[ni][2];
                }
                #pragma unroll
                for (int mask = 1; mask <= 8; mask <<= 1) {
                    s0 += __shfl_xor(s0, mask);
                    s1 += __shfl_xor(s1, mask);
                    s2 += __shfl_xor(s2, mask);
                }
                if (col16 == 0) {
                    const int m = m0 + wm * 64 + mi * 16 + quad * 4 + r;
                    if (m < NLINES) {
                        atomicAdd(&out[m * 3 + 0], s0 + (addb3 ? b3[0] : 0.f));
                        atomicAdd(&out[m * 3 + 1], s1 + (addb3 ? b3[1] : 0.f));
                        atomicAdd(&out[m * 3 + 2], s2 + (addb3 ? b3[2] : 0.f));
                    }
                }
            }
        }
    }
}

// ---------------------------------------------------------------------------
extern "C" void kernel_launch(void* const* d_in, const int* in_sizes, int n_in,
                              void* d_out, int out_size, void* d_ws, size_t ws_size,
                              hipStream_t stream)
{
    const float* jloc = (const float*)d_in[0];
    const float* joff = (const float*)d_in[1];
    const float* loi  = (const float*)d_in[2];
    const int*   eidx = (const int*)d_in[3];
    const float* W1   = (const float*)d_in[4];
    const float* b1   = (const float*)d_in[5];
    const float* W2   = (const float*)d_in[6];
    const float* b2   = (const float*)d_in[7];
    const float* W3   = (const float*)d_in[8];
    const float* b3   = (const float*)d_in[9];
    float* out = (float*)d_out;

    char* ws = (char*)d_ws;
    f16*   loiT  = (f16*)(ws);                            // 4 MB
    f16*   W1T   = (f16*)(ws + ((size_t)4 << 20));        // 2 MB
    f16*   W2T   = (f16*)(ws + ((size_t)6 << 20));        // 2 MB
    float* juncs = (float*)(ws + ((size_t)8 << 20));      // 2.4 KB
    int*   count = (int*)(ws + ((size_t)8 << 20) + 4096);
    unsigned long long* cand =
        (unsigned long long*)(ws + ((size_t)8 << 20) + 8192);  // 32 KB
    f16*   feats = (f16*)(ws + ((size_t)9 << 20));        // 40 MB (MPAD x 1024)
    f16*   h1    = (f16*)(ws + ((size_t)51 << 20));       // 40 MB

    hipMemsetAsync(out, 0, (size_t)out_size * sizeof(float), stream);
    hipMemsetAsync(count, 0, sizeof(int), stream);
    preproc_kernel<<<dim3(704), dim3(256), 0, stream>>>(
        loi, loiT, W1, W1T, W2, W2T, jloc, cand, count);
    rank_junc_kernel<<<dim3(MAXCAND / 256), dim3(256), 0, stream>>>(
        cand, count, joff, juncs);
    sample_kernel<<<dim3(NLINES / 4), dim3(256), 0, stream>>>(loiT, juncs, eidx, feats);
    gemm_bias_relu_kernel<<<dim3(MPAD / 128, NDIM / 128), dim3(256), 0, stream>>>(
        feats, W1T, b1, h1, nullptr, nullptr, nullptr, KDIM, 0);
    gemm_bias_relu_kernel<<<dim3(MPAD / 128, NDIM / 128), dim3(256), 0, stream>>>(
        h1, W2T, b2, nullptr, W3, b3, out, KDIM, 1);
}